// Round 1
// baseline (59276.691 us; speedup 1.0000x reference)
//
#include <hip/hip_runtime.h>
#include <hip/hip_cooperative_groups.h>

namespace cg = cooperative_groups;

#define DIMS 32
#define BLOCK 256

// Monotone map: smaller float  -> smaller u64 key; ties -> smaller index wins
// (matches jnp.argmin first-occurrence semantics).
__device__ __forceinline__ unsigned long long pack_min(float v, unsigned idx) {
    unsigned u = __float_as_uint(v);
    u = (u & 0x80000000u) ? ~u : (u | 0x80000000u);
    return ((unsigned long long)u << 32) | (unsigned long long)idx;
}

__device__ __forceinline__ unsigned long long shfl_down_u64(unsigned long long v, int off) {
    unsigned lo = (unsigned)(v & 0xffffffffu);
    unsigned hi = (unsigned)(v >> 32);
    lo = __shfl_down(lo, off, 64);
    hi = __shfl_down(hi, off, 64);
    return ((unsigned long long)hi << 32) | (unsigned long long)lo;
}

// Full-block min reduction; every thread returns the block-wide min.
__device__ __forceinline__ unsigned long long block_min_reduce(unsigned long long v,
                                                              unsigned long long* scratch) {
    #pragma unroll
    for (int off = 32; off >= 1; off >>= 1) {
        unsigned long long o = shfl_down_u64(v, off);
        v = (o < v) ? o : v;
    }
    const int wave = threadIdx.x >> 6;
    const int lane = threadIdx.x & 63;
    if (lane == 0) scratch[wave] = v;
    __syncthreads();
    unsigned long long r = scratch[0];
    #pragma unroll
    for (int i = 1; i < (BLOCK / 64); ++i) {
        unsigned long long o = scratch[i];
        r = (o < r) ? o : r;
    }
    __syncthreads();  // scratch safe for reuse
    return r;
}

__global__ __launch_bounds__(BLOCK, 2) void stein_thin_kernel(
    const float* __restrict__ x, const float* __restrict__ log_p,
    const float* __restrict__ score_p, const float* __restrict__ laplace,
    const float* __restrict__ ls_ptr, int* __restrict__ out,
    float* __restrict__ obj, unsigned long long* __restrict__ partial,
    int N, int m)
{
    cg::grid_group grid = cg::this_grid();
    const int tid = blockIdx.x * blockDim.x + threadIdx.x;
    const int T = gridDim.x * blockDim.x;
    const int G = gridDim.x;

    const float ell = ls_ptr[0];
    const float ell2 = ell * ell;
    const float w = 1.0f / (float)m;                 // weight_entropy = 1/m
    const float dim_over_ell2 = (float)DIMS / ell2;

    const float4* __restrict__ X4 = (const float4*)x;
    const float4* __restrict__ S4 = (const float4*)score_p;

    __shared__ float4 xi4[8];
    __shared__ float4 si4[8];
    __shared__ unsigned long long red_scratch[BLOCK / 64];

    // ---------- step 0: obj0 = d/ell2 + ||s||^2 + laplace - w*log_p ----------
    unsigned long long best = ~0ULL;
    for (int j = tid; j < N; j += T) {
        const size_t base = (size_t)j * (DIMS / 4);
        float ss = 0.0f;
        #pragma unroll
        for (int v = 0; v < DIMS / 4; ++v) {
            const float4 s = S4[base + v];
            ss += s.x * s.x; ss += s.y * s.y; ss += s.z * s.z; ss += s.w * s.w;
        }
        const float o = ((dim_over_ell2 + ss) + laplace[j]) - w * log_p[j];
        obj[j] = o;
        const unsigned long long p = pack_min(o, (unsigned)j);
        if (p < best) best = p;
    }
    {
        unsigned long long b = block_min_reduce(best, red_scratch);
        if (threadIdx.x == 0)
            __hip_atomic_store(&partial[blockIdx.x], b, __ATOMIC_RELAXED,
                               __HIP_MEMORY_SCOPE_AGENT);   // buffer 0
    }
    grid.sync();

    // ---------- steps 1..m-1 ----------
    for (int t = 1; t < m; ++t) {
        // Every block redundantly reduces previous step's partials (no 2nd sync,
        // no atomic hotspot); u64 min is associative -> identical result everywhere.
        const unsigned long long* pprev = partial + (size_t)((t - 1) & 1) * G;
        unsigned long long lb = ~0ULL;
        for (int i = threadIdx.x; i < G; i += BLOCK) {
            const unsigned long long p = __hip_atomic_load(&pprev[i], __ATOMIC_RELAXED,
                                                           __HIP_MEMORY_SCOPE_AGENT);
            if (p < lb) lb = p;
        }
        const unsigned long long gmin = block_min_reduce(lb, red_scratch);
        const int idx = (int)(gmin & 0xffffffffu);
        if (blockIdx.x == 0 && threadIdx.x == 0) out[t - 1] = idx;

        // Stage pivot x[idx], s[idx] into LDS, then registers.
        if (threadIdx.x < 16) {
            const size_t pb = (size_t)idx * (DIMS / 4);
            if (threadIdx.x < 8) xi4[threadIdx.x] = X4[pb + threadIdx.x];
            else                 si4[threadIdx.x - 8] = S4[pb + (threadIdx.x - 8)];
        }
        __syncthreads();

        float4 xr[DIMS / 4], sr[DIMS / 4];
        #pragma unroll
        for (int v = 0; v < DIMS / 4; ++v) { xr[v] = xi4[v]; sr[v] = si4[v]; }

        unsigned long long lbest = ~0ULL;
        for (int j = tid; j < N; j += T) {
            const size_t base = (size_t)j * (DIMS / 4);
            float r2 = 0.0f, c1 = 0.0f, c2 = 0.0f, dss = 0.0f;
            #pragma unroll
            for (int v = 0; v < DIMS / 4; ++v) {
                const float4 xv = X4[base + v];
                const float4 sv = S4[base + v];
                const float4 xp = xr[v];
                const float4 sp = sr[v];
                float d;
                d = xp.x - xv.x; r2 += d * d; c1 += d * sp.x; c2 += sv.x * d; dss += sv.x * sp.x;
                d = xp.y - xv.y; r2 += d * d; c1 += d * sp.y; c2 += sv.y * d; dss += sv.y * sp.y;
                d = xp.z - xv.z; r2 += d * d; c1 += d * sp.z; c2 += sv.z * d; dss += sv.z * sp.z;
                d = xp.w - xv.w; r2 += d * d; c1 += d * sp.w; c2 += sv.w * d; dss += sv.w * sp.w;
            }
            const float q   = 1.0f + r2 / ell2;
            const float qi  = 1.0f / q;
            const float sq  = sqrtf(qi);        // q^-0.5
            const float g   = qi * sq;          // q^-1.5
            const float q25 = qi * qi * sq;     // q^-2.5
            const float cross = (c1 - c2) / ell2;
            const float k = ((dim_over_ell2 * g - 3.0f * r2 / (ell2 * ell2) * q25)
                             + cross * g) + dss * sq;
            const float o = obj[j] + (2.0f * k - w * log_p[j]);
            obj[j] = o;
            const unsigned long long p = pack_min(o, (unsigned)j);
            if (p < lbest) lbest = p;
        }
        {
            unsigned long long b = block_min_reduce(lbest, red_scratch);
            if (threadIdx.x == 0)
                __hip_atomic_store(&partial[(size_t)(t & 1) * G + blockIdx.x], b,
                                   __ATOMIC_RELAXED, __HIP_MEMORY_SCOPE_AGENT);
        }
        grid.sync();
    }

    // ---------- final argmin -> out[m-1] ----------
    {
        const unsigned long long* pprev = partial + (size_t)((m - 1) & 1) * G;
        unsigned long long lb = ~0ULL;
        for (int i = threadIdx.x; i < G; i += BLOCK) {
            const unsigned long long p = __hip_atomic_load(&pprev[i], __ATOMIC_RELAXED,
                                                           __HIP_MEMORY_SCOPE_AGENT);
            if (p < lb) lb = p;
        }
        const unsigned long long gmin = block_min_reduce(lb, red_scratch);
        if (blockIdx.x == 0 && threadIdx.x == 0) out[m - 1] = (int)(gmin & 0xffffffffu);
    }
}

extern "C" void kernel_launch(void* const* d_in, const int* in_sizes, int n_in,
                              void* d_out, int out_size, void* d_ws, size_t ws_size,
                              hipStream_t stream) {
    const float* x        = (const float*)d_in[0];
    const float* log_p    = (const float*)d_in[1];
    const float* score_p  = (const float*)d_in[2];
    const float* laplace  = (const float*)d_in[3];
    const float* ls_ptr   = (const float*)d_in[4];
    // d_in[5] is m on device; host-side m == out_size.

    int* out = (int*)d_out;
    const int N = in_sizes[1];        // log_p has N elements
    const int m = out_size;

    float* obj = (float*)d_ws;
    size_t obj_bytes = ((size_t)N * sizeof(float) + 255) & ~(size_t)255;
    unsigned long long* partial = (unsigned long long*)((char*)d_ws + obj_bytes);

    // Cooperative launch: grid must be co-resident. 2 blocks/CU x 256 CUs.
    int occ = 0;
    hipOccupancyMaxActiveBlocksPerMultiprocessor(&occ, (const void*)stein_thin_kernel,
                                                 BLOCK, 0);
    if (occ < 1) occ = 1;
    int G = occ * 256;                 // 256 CUs on MI355X
    if (G > 512) G = 512;              // partial buffer sized for <=1024; cap at 2/CU

    void* args[] = {(void*)&x, (void*)&log_p, (void*)&score_p, (void*)&laplace,
                    (void*)&ls_ptr, (void*)&out, (void*)&obj, (void*)&partial,
                    (void*)&N, (void*)&m};
    hipLaunchCooperativeKernel((void*)stein_thin_kernel, dim3(G), dim3(BLOCK),
                               args, 0, stream);
}

// Round 3
// 23368.854 us; speedup vs baseline: 2.5366x; 2.5366x over previous
//
#include <hip/hip_runtime.h>

#define BLOCK 512
#define GRID  256          // = #CUs: 1 block/CU guaranteed => coop launch cannot fail
#define PPT   4            // GRID*BLOCK*PPT = 524288 >= N
#define V     8            // DIMS/4 float4s per row
#define DIMS  32
#define SLOTS_PER_THREAD (GRID / 64)   // wave-0 gather: 4 slots per lane

// Monotone map: smaller float -> smaller u32 key (ties broken by index).
__device__ __forceinline__ unsigned pack_f32(float v) {
    unsigned u = __float_as_uint(v);
    return (u & 0x80000000u) ? ~u : (u | 0x80000000u);
}

__device__ __forceinline__ unsigned long long pack_min(float v, unsigned idx) {
    return ((unsigned long long)pack_f32(v) << 32) | (unsigned long long)idx;
}

__device__ __forceinline__ unsigned long long shfl_down_u64(unsigned long long v, int off) {
    unsigned lo = (unsigned)(v & 0xffffffffu);
    unsigned hi = (unsigned)(v >> 32);
    lo = __shfl_down(lo, off, 64);
    hi = __shfl_down(hi, off, 64);
    return ((unsigned long long)hi << 32) | (unsigned long long)lo;
}

// Full-block min reduction; every thread returns the block-wide min.
__device__ __forceinline__ unsigned long long block_min_reduce(unsigned long long v,
                                                              unsigned long long* scratch) {
    #pragma unroll
    for (int off = 32; off >= 1; off >>= 1) {
        unsigned long long o = shfl_down_u64(v, off);
        v = (o < v) ? o : v;
    }
    const int wave = threadIdx.x >> 6;
    const int lane = threadIdx.x & 63;
    if (lane == 0) scratch[wave] = v;
    __syncthreads();
    unsigned long long r = scratch[0];
    #pragma unroll
    for (int i = 1; i < (BLOCK / 64); ++i) {
        unsigned long long o = scratch[i];
        r = (o < r) ? o : r;
    }
    __syncthreads();  // scratch safe for reuse
    return r;
}

// Post this block's min for step t. Slot key: [val:32 | step:12 | idx:20].
__device__ __forceinline__ void post_slot(unsigned long long* __restrict__ slots,
                                          unsigned long long blockmin, int t) {
    if (threadIdx.x == 0) {
        const unsigned long long val = blockmin >> 32;
        const unsigned long long idx = blockmin & 0xFFFFFull;   // all idx < 2^20
        const unsigned long long key =
            (val << 32) | ((unsigned long long)((unsigned)t & 0xFFFu) << 20) | idx;
        __hip_atomic_store(&slots[(size_t)(t & 1) * GRID + blockIdx.x], key,
                           __ATOMIC_RELAXED, __HIP_MEMORY_SCOPE_AGENT);
    }
}

// Wave 0 polls all GRID slots for step t (4 per lane, loads issued back-to-back
// so stale slots cost one extra round-trip, not four). Other waves wait at the
// barrier with zero memory traffic. Returns grid-wide min to ALL threads.
__device__ __forceinline__ unsigned long long gather_min(
    const unsigned long long* __restrict__ slotp, int t,
    unsigned long long* red_scratch, unsigned long long* gmin_sh) {
    if (threadIdx.x < 64) {
        const unsigned want = (unsigned)t & 0xFFFu;
        unsigned long long k[SLOTS_PER_THREAD];
        for (;;) {
            #pragma unroll
            for (int s = 0; s < SLOTS_PER_THREAD; ++s)
                k[s] = __hip_atomic_load(&slotp[threadIdx.x + 64 * s],
                                         __ATOMIC_RELAXED, __HIP_MEMORY_SCOPE_AGENT);
            bool ok = true;
            #pragma unroll
            for (int s = 0; s < SLOTS_PER_THREAD; ++s)
                ok &= (((unsigned)(k[s] >> 20) & 0xFFFu) == want);
            if (ok) break;
        }
        unsigned long long lb = k[0];
        #pragma unroll
        for (int s = 1; s < SLOTS_PER_THREAD; ++s)
            if (k[s] < lb) lb = k[s];
        #pragma unroll
        for (int off = 32; off >= 1; off >>= 1) {
            unsigned long long o = shfl_down_u64(lb, off);
            lb = (o < lb) ? o : lb;
        }
        if (threadIdx.x == 0) *gmin_sh = lb;
    }
    __syncthreads();
    unsigned long long r = *gmin_sh;
    __syncthreads();
    (void)red_scratch;
    return r;
}

__global__ __launch_bounds__(BLOCK, 2) void stein_thin_persist(
    const float* __restrict__ x, const float* __restrict__ log_p,
    const float* __restrict__ score_p, const float* __restrict__ laplace,
    const float* __restrict__ ls_ptr, int* __restrict__ out,
    unsigned long long* __restrict__ slots, int N, int m)
{
    const int tid = blockIdx.x * BLOCK + threadIdx.x;
    const int T = GRID * BLOCK;          // 131072

    const float ell = ls_ptr[0];
    const float ell2 = ell * ell;
    const float w = 1.0f / (float)m;                 // weight_entropy = 1/m
    const float dim_over_ell2 = (float)DIMS / ell2;

    const float4* __restrict__ X4 = (const float4*)x;
    const float4* __restrict__ S4 = (const float4*)score_p;

    __shared__ float4 xi4[V];
    __shared__ float4 si4[V];
    __shared__ unsigned long long red_scratch[BLOCK / 64];
    __shared__ unsigned long long gmin_sh;

    // -------- persistent per-thread state: x rows, obj, log_p in registers ----
    float4 xr[PPT][V];                 // 128 VGPRs: this thread's 4 x-rows
    const float4* sptr[PPT];           // per-point base pointer into S
    float objr[PPT], lpr[PPT];

    {
        unsigned long long lbest = ~0ULL;
        #pragma unroll
        for (int p = 0; p < PPT; ++p) {
            const int j = tid + p * T;
            const bool act = (j < N);
            const int jc = act ? j : (N - 1);        // clamp: loads stay in-bounds
            const size_t base = (size_t)jc * V;
            sptr[p] = S4 + base;
            float ss = 0.0f;
            #pragma unroll
            for (int v = 0; v < V; ++v) {
                const float4 s = S4[base + v];
                xr[p][v] = X4[base + v];
                ss += s.x * s.x; ss += s.y * s.y; ss += s.z * s.z; ss += s.w * s.w;
            }
            lpr[p] = log_p[jc];
            // identical source shape to the verified round-1 kernel:
            float o = ((dim_over_ell2 + ss) + laplace[jc]) - w * log_p[jc];
            if (!act) o = __int_as_float(0x7F800000);   // +inf: never selected
            objr[p] = o;
            const unsigned long long pk = pack_min(o, (unsigned)j);
            if (pk < lbest) lbest = pk;
        }
        post_slot(slots, block_min_reduce(lbest, red_scratch), 0);
    }

    // -------- steps 1..m-1: gather -> pivot -> update pass -> post ------------
    for (int t = 1; t < m; ++t) {
        const unsigned long long gmin =
            gather_min(slots + (size_t)((t - 1) & 1) * GRID, t - 1, red_scratch, &gmin_sh);
        const int idx = (int)(gmin & 0xFFFFFull);
        if (blockIdx.x == 0 && threadIdx.x == 0) out[t - 1] = idx;

        // stage pivot row (x[idx], s[idx]) into LDS
        if (threadIdx.x < 16) {
            const size_t pb = (size_t)idx * V;
            if (threadIdx.x < 8) xi4[threadIdx.x] = X4[pb + threadIdx.x];
            else                 si4[threadIdx.x - 8] = S4[pb + (threadIdx.x - 8)];
        }
        __syncthreads();

        float r2[PPT], c1[PPT], c2[PPT], dss[PPT];
        #pragma unroll
        for (int p = 0; p < PPT; ++p) { r2[p] = 0.0f; c1[p] = 0.0f; c2[p] = 0.0f; dss[p] = 0.0f; }

        #pragma unroll
        for (int v = 0; v < V; ++v) {
            const float4 xp = xi4[v];
            const float4 sp = si4[v];
            #pragma unroll
            for (int p = 0; p < PPT; ++p) {
                const float4 xv = xr[p][v];
                const float4 sv = sptr[p][v];
                float d;
                d = xp.x - xv.x; r2[p] += d * d; c1[p] += d * sp.x; c2[p] += sv.x * d; dss[p] += sv.x * sp.x;
                d = xp.y - xv.y; r2[p] += d * d; c1[p] += d * sp.y; c2[p] += sv.y * d; dss[p] += sv.y * sp.y;
                d = xp.z - xv.z; r2[p] += d * d; c1[p] += d * sp.z; c2[p] += sv.z * d; dss[p] += sv.z * sp.z;
                d = xp.w - xv.w; r2[p] += d * d; c1[p] += d * sp.w; c2[p] += sv.w * d; dss[p] += sv.w * sp.w;
            }
        }

        unsigned long long lbest = ~0ULL;
        #pragma unroll
        for (int p = 0; p < PPT; ++p) {
            const float q   = 1.0f + r2[p] / ell2;
            const float qi  = 1.0f / q;
            const float sq  = sqrtf(qi);        // q^-0.5
            const float g   = qi * sq;          // q^-1.5
            const float q25 = qi * qi * sq;     // q^-2.5
            const float cross = (c1[p] - c2[p]) / ell2;
            const float k = ((dim_over_ell2 * g - 3.0f * r2[p] / (ell2 * ell2) * q25)
                             + cross * g) + dss[p] * sq;
            // +inf rows stay +inf (their loads were clamped to a real row => k finite)
            const float o = objr[p] + (2.0f * k - w * lpr[p]);
            objr[p] = o;
            const unsigned long long pk = pack_min(o, (unsigned)(tid + p * T));
            if (pk < lbest) lbest = pk;
        }
        post_slot(slots, block_min_reduce(lbest, red_scratch), t);
    }

    // -------- final argmin -> out[m-1] ----------------------------------------
    {
        const unsigned long long gmin =
            gather_min(slots + (size_t)((m - 1) & 1) * GRID, m - 1, red_scratch, &gmin_sh);
        if (blockIdx.x == 0 && threadIdx.x == 0) out[m - 1] = (int)(gmin & 0xFFFFFull);
    }
}

extern "C" void kernel_launch(void* const* d_in, const int* in_sizes, int n_in,
                              void* d_out, int out_size, void* d_ws, size_t ws_size,
                              hipStream_t stream) {
    const float* x        = (const float*)d_in[0];
    const float* log_p    = (const float*)d_in[1];
    const float* score_p  = (const float*)d_in[2];
    const float* laplace  = (const float*)d_in[3];
    const float* ls_ptr   = (const float*)d_in[4];

    int* out = (int*)d_out;
    int N = in_sizes[1];            // log_p has N elements
    int m = out_size;

    unsigned long long* slots = (unsigned long long*)d_ws;  // 2*GRID u64 = 4 KB

    void* args[] = {(void*)&x, (void*)&log_p, (void*)&score_p, (void*)&laplace,
                    (void*)&ls_ptr, (void*)&out, (void*)&slots, (void*)&N, (void*)&m};
    hipError_t err = hipLaunchCooperativeKernel((void*)stein_thin_persist,
                                                dim3(GRID), dim3(BLOCK), args, 0, stream);
    if (err != hipSuccess) {
        // 1 block/CU is occupancy-guaranteed (<=256 VGPR by launch_bounds, ~330 B LDS),
        // so a plain 256-block launch is still fully co-resident.
        (void)hipGetLastError();   // clear error state
        stein_thin_persist<<<dim3(GRID), dim3(BLOCK), 0, stream>>>(
            x, log_p, score_p, laplace, ls_ptr, out, slots, N, m);
    }
}

// Round 4
// 18711.531 us; speedup vs baseline: 3.1679x; 1.2489x over previous
//
#include <hip/hip_runtime.h>

#define BLOCK 512
#define GRID  256          // = #CUs: 1 block/CU, co-resident
#define PPT   4            // GRID*BLOCK*PPT = 524288 >= N
#define V     8            // DIMS/4 float4s per row
#define DIMS  32
#define SLOTS_PER_THREAD (GRID / 64)   // wave-0 gather: 4 slots per lane

// Monotone map: smaller float -> smaller u32 key (ties broken by index).
__device__ __forceinline__ unsigned pack_f32(float v) {
    unsigned u = __float_as_uint(v);
    return (u & 0x80000000u) ? ~u : (u | 0x80000000u);
}

__device__ __forceinline__ unsigned long long pack_min(float v, unsigned idx) {
    return ((unsigned long long)pack_f32(v) << 32) | (unsigned long long)idx;
}

__device__ __forceinline__ unsigned long long shfl_down_u64(unsigned long long v, int off) {
    unsigned lo = (unsigned)(v & 0xffffffffu);
    unsigned hi = (unsigned)(v >> 32);
    lo = __shfl_down(lo, off, 64);
    hi = __shfl_down(hi, off, 64);
    return ((unsigned long long)hi << 32) | (unsigned long long)lo;
}

// Full-block min reduction; every thread returns the block-wide min.
__device__ __forceinline__ unsigned long long block_min_reduce(unsigned long long v,
                                                              unsigned long long* scratch) {
    #pragma unroll
    for (int off = 32; off >= 1; off >>= 1) {
        unsigned long long o = shfl_down_u64(v, off);
        v = (o < v) ? o : v;
    }
    const int wave = threadIdx.x >> 6;
    const int lane = threadIdx.x & 63;
    if (lane == 0) scratch[wave] = v;
    __syncthreads();
    unsigned long long r = scratch[0];
    #pragma unroll
    for (int i = 1; i < (BLOCK / 64); ++i) {
        unsigned long long o = scratch[i];
        r = (o < r) ? o : r;
    }
    __syncthreads();  // scratch safe for reuse
    return r;
}

// Post this block's min for step t. Slot key: [val:32 | step:12 | idx:20].
__device__ __forceinline__ void post_slot(unsigned long long* __restrict__ slots,
                                          unsigned long long blockmin, int t) {
    if (threadIdx.x == 0) {
        const unsigned long long val = blockmin >> 32;
        const unsigned long long idx = blockmin & 0xFFFFFull;   // all idx < 2^20
        const unsigned long long key =
            (val << 32) | ((unsigned long long)((unsigned)t & 0xFFFu) << 20) | idx;
        __hip_atomic_store(&slots[(size_t)(t & 1) * GRID + blockIdx.x], key,
                           __ATOMIC_RELAXED, __HIP_MEMORY_SCOPE_AGENT);
    }
}

// Wave 0 polls all GRID slots for step t; other waves wait at the barrier with
// zero memory traffic. Returns grid-wide min to ALL threads.
__device__ __forceinline__ unsigned long long gather_min(
    const unsigned long long* __restrict__ slotp, int t, unsigned long long* gmin_sh) {
    if (threadIdx.x < 64) {
        const unsigned want = (unsigned)t & 0xFFFu;
        unsigned long long k[SLOTS_PER_THREAD];
        for (;;) {
            #pragma unroll
            for (int s = 0; s < SLOTS_PER_THREAD; ++s)
                k[s] = __hip_atomic_load(&slotp[threadIdx.x + 64 * s],
                                         __ATOMIC_RELAXED, __HIP_MEMORY_SCOPE_AGENT);
            bool ok = true;
            #pragma unroll
            for (int s = 0; s < SLOTS_PER_THREAD; ++s)
                ok &= (((unsigned)(k[s] >> 20) & 0xFFFu) == want);
            if (ok) break;
        }
        unsigned long long lb = k[0];
        #pragma unroll
        for (int s = 1; s < SLOTS_PER_THREAD; ++s)
            if (k[s] < lb) lb = k[s];
        #pragma unroll
        for (int off = 32; off >= 1; off >>= 1) {
            unsigned long long o = shfl_down_u64(lb, off);
            lb = (o < lb) ? o : lb;
        }
        if (threadIdx.x == 0) *gmin_sh = lb;
    }
    __syncthreads();
    unsigned long long r = *gmin_sh;
    __syncthreads();
    return r;
}

// LDS_PTS = how many of this thread's PPT points keep their S-row in LDS.
// LDS_PTS=2 -> 128 KB LDS tier (gfx950 has 160 KB/CU); LDS_PTS=1 -> 64 KB.
template<int LDS_PTS>
__global__ __launch_bounds__(BLOCK) __attribute__((amdgpu_waves_per_eu(2, 2)))
void stein_thin_persist(
    const float* __restrict__ x, const float* __restrict__ log_p,
    const float* __restrict__ score_p, const float* __restrict__ laplace,
    const float* __restrict__ ls_ptr, int* __restrict__ out,
    unsigned long long* __restrict__ slots, int N, int m)
{
    const int tid = blockIdx.x * BLOCK + threadIdx.x;
    const int T = GRID * BLOCK;          // 131072

    const float ell = ls_ptr[0];
    const float ell2 = ell * ell;
    const float w = 1.0f / (float)m;                 // weight_entropy = 1/m
    const float dim_over_ell2 = (float)DIMS / ell2;

    const float4* __restrict__ X4 = (const float4*)x;
    const float4* __restrict__ S4 = (const float4*)score_p;

    // Transposed S tier: s_ldsT[v][p*BLOCK + t] = S4[row(p,t)*V + v].
    // Per step, lane reads its own 16B chunk -> canonical conflict-free b128.
    __shared__ float4 s_ldsT[V][LDS_PTS * BLOCK];
    __shared__ float4 xi4[V];
    __shared__ float4 si4[V];
    __shared__ unsigned long long gmin_sh;

    // -------- persistent per-thread state ------------------------------------
    float4 xr[PPT][V];                 // 128 VGPRs: this thread's 4 x-rows
    const float4* sptr[PPT];           // base pointers into S (streamed tiers)
    float objr[PPT], lpr[PPT];

    {
        __shared__ unsigned long long red_scratch_i[BLOCK / 64];
        unsigned long long lbest = ~0ULL;
        #pragma unroll
        for (int p = 0; p < PPT; ++p) {
            const int j = tid + p * T;
            const bool act = (j < N);
            const int jc = act ? j : (N - 1);        // clamp: loads stay in-bounds
            const size_t base = (size_t)jc * V;
            sptr[p] = S4 + base;
            float ss = 0.0f;
            #pragma unroll
            for (int v = 0; v < V; ++v) {
                const float4 s = S4[base + v];
                if (p < LDS_PTS) s_ldsT[v][p * BLOCK + threadIdx.x] = s;
                xr[p][v] = X4[base + v];
                ss += s.x * s.x; ss += s.y * s.y; ss += s.z * s.z; ss += s.w * s.w;
            }
            lpr[p] = log_p[jc];
            // identical source shape to the verified round-1/3 kernel:
            float o = ((dim_over_ell2 + ss) + laplace[jc]) - w * log_p[jc];
            if (!act) o = __int_as_float(0x7F800000);   // +inf: never selected
            objr[p] = o;
            const unsigned long long pk = pack_min(o, (unsigned)j);
            if (pk < lbest) lbest = pk;
        }
        post_slot(slots, block_min_reduce(lbest, red_scratch_i), 0);
    }
    __syncthreads();   // s_ldsT fully populated before the step loop

    // -------- steps 1..m-1: gather -> pivot -> update pass -> post ------------
    for (int t = 1; t < m; ++t) {
        const unsigned long long gmin =
            gather_min(slots + (size_t)((t - 1) & 1) * GRID, t - 1, &gmin_sh);
        const int idx = (int)(gmin & 0xFFFFFull);
        if (blockIdx.x == 0 && threadIdx.x == 0) out[t - 1] = idx;

        // stage pivot row (x[idx], s[idx]) into LDS (L2-hit global read)
        if (threadIdx.x < 16) {
            const size_t pb = (size_t)idx * V;
            if (threadIdx.x < 8) xi4[threadIdx.x] = X4[pb + threadIdx.x];
            else                 si4[threadIdx.x - 8] = S4[pb + (threadIdx.x - 8)];
        }
        __syncthreads();

        unsigned long long lbest = ~0ULL;
        #pragma unroll
        for (int p = 0; p < PPT; ++p) {
            float r2 = 0.0f, c1 = 0.0f, c2 = 0.0f, dss = 0.0f;
            #pragma unroll
            for (int v = 0; v < V; ++v) {
                const float4 xp = xi4[v];
                const float4 sp = si4[v];
                const float4 xv = xr[p][v];
                const float4 sv = (p < LDS_PTS) ? s_ldsT[v][p * BLOCK + threadIdx.x]
                                                : sptr[p][v];
                float d;
                d = xp.x - xv.x; r2 += d * d; c1 += d * sp.x; c2 += sv.x * d; dss += sv.x * sp.x;
                d = xp.y - xv.y; r2 += d * d; c1 += d * sp.y; c2 += sv.y * d; dss += sv.y * sp.y;
                d = xp.z - xv.z; r2 += d * d; c1 += d * sp.z; c2 += sv.z * d; dss += sv.z * sp.z;
                d = xp.w - xv.w; r2 += d * d; c1 += d * sp.w; c2 += sv.w * d; dss += sv.w * sp.w;
            }
            const float q   = 1.0f + r2 / ell2;
            const float qi  = 1.0f / q;
            const float sq  = sqrtf(qi);        // q^-0.5
            const float g   = qi * sq;          // q^-1.5
            const float q25 = qi * qi * sq;     // q^-2.5
            const float cross = (c1 - c2) / ell2;
            const float k = ((dim_over_ell2 * g - 3.0f * r2 / (ell2 * ell2) * q25)
                             + cross * g) + dss * sq;
            // +inf rows stay +inf (their loads were clamped to a real row => k finite)
            const float o = objr[p] + (2.0f * k - w * lpr[p]);
            objr[p] = o;
            const unsigned long long pk = pack_min(o, (unsigned)(tid + p * T));
            if (pk < lbest) lbest = pk;
        }
        // reuse xi4 as reduce scratch is unsafe (pivot); use a small local one:
        {
            __shared__ unsigned long long red_scratch[BLOCK / 64];
            post_slot(slots, block_min_reduce(lbest, red_scratch), t);
        }
    }

    // -------- final argmin -> out[m-1] ----------------------------------------
    {
        const unsigned long long gmin =
            gather_min(slots + (size_t)((m - 1) & 1) * GRID, m - 1, &gmin_sh);
        if (blockIdx.x == 0 && threadIdx.x == 0) out[m - 1] = (int)(gmin & 0xFFFFFull);
    }
}

extern "C" void kernel_launch(void* const* d_in, const int* in_sizes, int n_in,
                              void* d_out, int out_size, void* d_ws, size_t ws_size,
                              hipStream_t stream) {
    const float* x        = (const float*)d_in[0];
    const float* log_p    = (const float*)d_in[1];
    const float* score_p  = (const float*)d_in[2];
    const float* laplace  = (const float*)d_in[3];
    const float* ls_ptr   = (const float*)d_in[4];

    int* out = (int*)d_out;
    int N = in_sizes[1];            // log_p has N elements
    int m = out_size;

    unsigned long long* slots = (unsigned long long*)d_ws;  // 2*GRID u64 = 4 KB

    void* args[] = {(void*)&x, (void*)&log_p, (void*)&score_p, (void*)&laplace,
                    (void*)&ls_ptr, (void*)&out, (void*)&slots, (void*)&N, (void*)&m};

    // Preferred: 128 KB LDS tier (2 of 4 points' S-rows LDS-resident).
    hipError_t err = hipLaunchCooperativeKernel((void*)stein_thin_persist<2>,
                                                dim3(GRID), dim3(BLOCK), args, 0, stream);
    if (err != hipSuccess) {
        (void)hipGetLastError();
        // Fallback: 64 KB LDS tier (guaranteed on any CDNA).
        err = hipLaunchCooperativeKernel((void*)stein_thin_persist<1>,
                                         dim3(GRID), dim3(BLOCK), args, 0, stream);
    }
    if (err != hipSuccess) {
        (void)hipGetLastError();
        // 1 block/CU is occupancy-guaranteed -> plain launch is still co-resident.
        stein_thin_persist<1><<<dim3(GRID), dim3(BLOCK), 0, stream>>>(
            x, log_p, score_p, laplace, ls_ptr, out, slots, N, m);
    }
}